// Round 12
// baseline (245.753 us; speedup 1.0000x reference)
//
#include <hip/hip_runtime.h>

// AttentionLoRA: B=1, S=4096, D=1024, H=16, HD=64.
// Pipeline (4 kernels):
//   cvt_all (f32->bf16 + bias pack + RoPE table transpose fcT/fsT[32][4096])
//   gemm1: QKV NT-GEMM, 256x256 tile / BK=64 / 8 waves / 128KB dbuf LDS,
//          8-phase schedule with counted vmcnt (T3+T4), both-sides LDS swizzle.
//          Epilogue fuses RoPE (q/k; float4 loads from transposed tables) and
//          V-transpose -> vT (h,hd,s).
//   flash: R11 (proven): 1024 blocks x 512 thr, even/odd kv parity groups,
//          heavy-first queue; K dbuf 32KB + V single-buffer 16KB = 48KB LDS ->
//          3 blocks/CU (24 waves/CU) with 256-block queue; split-phase sync
//          {vmcnt0;barA; issue V(s),K(s+1); QK+exp2+pack; vmcnt;barB; PV}.
//   gemm2: out-proj, 128x64 tiles (512 blocks, 2/CU), f32 out.
// Session rules: grid must exceed residency slots (R6/R8); MFMA B-fragments
// direct from global are per-lane row-scattered -> LDS-stage them (R9).

#define S_LEN 4096
#define DIM   1024
#define NH    16
#define HD    64

typedef __attribute__((ext_vector_type(8))) short bf16x8;   // 8 bf16 = 4 VGPRs
typedef __attribute__((ext_vector_type(4))) float f32x4;

__device__ __forceinline__ unsigned short f2b(float f) {
  union { float f; unsigned int u; } v; v.f = f;
  unsigned int r = (v.u + 0x7fffu + ((v.u >> 16) & 1u)) >> 16;  // RNE
  return (unsigned short)r;
}
__device__ __forceinline__ float b2f(unsigned short h) {
  union { unsigned int u; float f; } v; v.u = ((unsigned int)h) << 16;
  return v.f;
}
// pack two f32 -> two bf16 by truncation (p in [0,1]; <=1ulp)
__device__ __forceinline__ unsigned int pk2t(float a, float b) {
  union { float f; unsigned int u; } x, y; x.f = a; y.f = b;
  return (x.u >> 16) | (y.u & 0xffff0000u);
}
__device__ __forceinline__ void gload16(const void* g, void* l) {
  __builtin_amdgcn_global_load_lds(
      (const __attribute__((address_space(1))) unsigned int*)g,
      (__attribute__((address_space(3))) unsigned int*)l, 16, 0, 0);
}
__device__ __forceinline__ f32x4 fzero4() { f32x4 z = {0.f, 0.f, 0.f, 0.f}; return z; }

// ---- LDS swizzled 16B read: row-major [rows][128B], chunk XOR row&7 -------------
__device__ __forceinline__ bf16x8 lds_swz(const unsigned short* s, int row, int chunk) {
  int byte = row * 128 + ((chunk ^ (row & 7)) << 4);
  return *(const bf16x8*)((const char*)s + byte);
}

// ---------------- fused f32->bf16 convert + bias pack + RoPE table transpose ------
__global__ void cvt_all(const float* __restrict__ x, const float* __restrict__ wq,
                        const float* __restrict__ wk, const float* __restrict__ wv,
                        const float* __restrict__ wo, const float* __restrict__ qb,
                        const float* __restrict__ kb, const float* __restrict__ vbs,
                        const float* __restrict__ ob, const float* __restrict__ fc,
                        const float* __restrict__ fs, unsigned short* __restrict__ xb,
                        unsigned short* __restrict__ wqkvb, unsigned short* __restrict__ wobb,
                        float* __restrict__ biasq, float* __restrict__ biaso,
                        float4* __restrict__ fcT4, float4* __restrict__ fsT4) {
  int i = blockIdx.x * 256 + threadIdx.x;  // float4 index
  if (i < 2097152) {
    const float* src; unsigned short* dst; int off;
    if (i < 1048576)      { src = x;  dst = xb;              off = i; }
    else if (i < 1310720) { src = wq; dst = wqkvb;           off = i - 1048576; }
    else if (i < 1572864) { src = wk; dst = wqkvb + 1048576; off = i - 1310720; }
    else if (i < 1835008) { src = wv; dst = wqkvb + 2097152; off = i - 1572864; }
    else                  { src = wo; dst = wobb;            off = i - 1835008; }
    float4 v = ((const float4*)src)[off];
    unsigned int lo = (unsigned int)f2b(v.x) | ((unsigned int)f2b(v.y) << 16);
    unsigned int hi = (unsigned int)f2b(v.z) | ((unsigned int)f2b(v.w) << 16);
    ((uint2*)dst)[off] = make_uint2(lo, hi);
  } else if (i < 2097152 + 1024) {
    int j = i - 2097152;
    if (j < 256)      ((float4*)biasq)[j]              = ((const float4*)qb)[j];
    else if (j < 512) ((float4*)(biasq + 1024))[j-256] = ((const float4*)kb)[j-256];
    else if (j < 768) ((float4*)(biasq + 2048))[j-512] = ((const float4*)vbs)[j-512];
    else              ((float4*)biaso)[j-768]          = ((const float4*)ob)[j-768];
  } else if (i < 2098176 + 65536) {
    // transpose fc/fs (S,32) -> fcT/fsT [32][4096] as float4 over m
    int j = i - 2098176;
    const float* src = (j < 32768) ? fc : fs;
    float4* dst = (j < 32768) ? fcT4 : fsT4;
    int jj = j & 32767;
    int pi = jj >> 10, m0 = (jj & 1023) << 2;
    float4 v;
    v.x = src[(m0 + 0) * 32 + pi];
    v.y = src[(m0 + 1) * 32 + pi];
    v.z = src[(m0 + 2) * 32 + pi];
    v.w = src[(m0 + 3) * 32 + pi];
    dst[jj] = v;
  }
}

// ---------------- gemm1: QKV NT-GEMM, 256x256/BK=64, 8-phase counted-vmcnt --------
__global__ __launch_bounds__(512, 2) void gemm_qkv(
    const unsigned short* __restrict__ A, const unsigned short* __restrict__ B,
    const float* __restrict__ bias, unsigned short* __restrict__ dq,
    unsigned short* __restrict__ dk, unsigned short* __restrict__ vtout,
    const float4* __restrict__ fcT4, const float4* __restrict__ fsT4, int K) {
  __shared__ alignas(16) unsigned short sA[2][256 * 64];  // 64KB
  __shared__ alignas(16) unsigned short sB[2][256 * 64];  // 64KB
  const int tid = threadIdx.x;
  const int lane = tid & 63, wave = tid >> 6;
  const int ln = lane & 15, quad = lane >> 4;
  const int bm = blockIdx.x * 256, bn = blockIdx.y * 256;
  const int wr = (wave >> 2) * 128, wc = (wave & 3) * 64;
  const int NT = K >> 6;  // 16 K-tiles

  f32x4 acc[8][4];
#pragma unroll
  for (int i = 0; i < 8; ++i)
#pragma unroll
    for (int j = 0; j < 4; ++j) acc[i][j] = fzero4();

#define STAGE(tt, ch) do {                                                   \
    int o_ = ((ch) * 512 + tid) * 8;                                         \
    int row_ = o_ >> 6, c_ = (o_ >> 3) & 7;                                  \
    int col_ = ((tt) << 6) + ((c_ ^ (row_ & 7)) << 3);                       \
    int bs_ = (tt) & 1;                                                      \
    gload16(A + (size_t)(bm + row_) * K + col_, (char*)sA[bs_] + o_ * 2);    \
    gload16(B + (size_t)(bn + row_) * K + col_, (char*)sB[bs_] + o_ * 2);    \
  } while (0)
#define BAR()   __builtin_amdgcn_s_barrier()
#define LGKM0() asm volatile("s_waitcnt lgkmcnt(0)" ::: "memory")

  STAGE(0, 0); STAGE(0, 1); STAGE(0, 2); STAGE(0, 3); STAGE(1, 0);
  asm volatile("s_waitcnt vmcnt(2)" ::: "memory");
  BAR();

#pragma unroll 2
  for (int t = 0; t < 16; ++t) {
    const unsigned short* cA = sA[t & 1];
    const unsigned short* cB = sB[t & 1];
    bf16x8 a0[4], a1[4], b0[4], b1[4];

    // ---- phase 0
#pragma unroll
    for (int j = 0; j < 4; ++j) b0[j] = lds_swz(cB, wc + j * 16 + ln, quad);
#pragma unroll
    for (int i = 0; i < 4; ++i) a0[i] = lds_swz(cA, wr + i * 16 + ln, quad);
    if (t + 1 < NT) STAGE(t + 1, 1);
    BAR(); LGKM0();
    __builtin_amdgcn_s_setprio(1);
#pragma unroll
    for (int i = 0; i < 4; ++i)
#pragma unroll
      for (int j = 0; j < 4; ++j)
        acc[i][j] = __builtin_amdgcn_mfma_f32_16x16x32_bf16(a0[i], b0[j], acc[i][j], 0, 0, 0);
    __builtin_amdgcn_s_setprio(0);
    BAR();

    // ---- phase 1
#pragma unroll
    for (int i = 0; i < 4; ++i) a1[i] = lds_swz(cA, wr + (i + 4) * 16 + ln, quad);
#pragma unroll
    for (int j = 0; j < 4; ++j) b1[j] = lds_swz(cB, wc + j * 16 + ln, 4 + quad);
    if (t + 1 < NT) STAGE(t + 1, 2);
    BAR(); LGKM0();
    __builtin_amdgcn_s_setprio(1);
#pragma unroll
    for (int i = 0; i < 4; ++i)
#pragma unroll
      for (int j = 0; j < 4; ++j)
        acc[i + 4][j] = __builtin_amdgcn_mfma_f32_16x16x32_bf16(a1[i], b0[j], acc[i + 4][j], 0, 0, 0);
    __builtin_amdgcn_s_setprio(0);
    BAR();

    // ---- phase 2
#pragma unroll
    for (int i = 0; i < 4; ++i) a0[i] = lds_swz(cA, wr + i * 16 + ln, 4 + quad);
#pragma unroll
    for (int i = 0; i < 4; ++i) a1[i] = lds_swz(cA, wr + (i + 4) * 16 + ln, 4 + quad);
    if (t + 1 < NT) STAGE(t + 1, 3);
    BAR(); LGKM0();
    __builtin_amdgcn_s_setprio(1);
#pragma unroll
    for (int i = 0; i < 4; ++i)
#pragma unroll
      for (int j = 0; j < 4; ++j)
        acc[i][j] = __builtin_amdgcn_mfma_f32_16x16x32_bf16(a0[i], b1[j], acc[i][j], 0, 0, 0);
    __builtin_amdgcn_s_setprio(0);
    BAR();

    // ---- phase 3
    if (t + 2 < NT) STAGE(t + 2, 0);
    BAR(); LGKM0();
    __builtin_amdgcn_s_setprio(1);
#pragma unroll
    for (int i = 0; i < 4; ++i)
#pragma unroll
      for (int j = 0; j < 4; ++j)
        acc[i + 4][j] = __builtin_amdgcn_mfma_f32_16x16x32_bf16(a1[i], b1[j], acc[i + 4][j], 0, 0, 0);
    __builtin_amdgcn_s_setprio(0);
    if (t < 14) {
      asm volatile("s_waitcnt vmcnt(2)" ::: "memory");
      BAR();
    } else if (t == 14) {
      asm volatile("s_waitcnt vmcnt(0)" ::: "memory");
      BAR();
    }
  }
#undef STAGE
#undef BAR
#undef LGKM0

  const int bufi = bn >> 10;                  // 0:q 1:k 2:v (block-uniform)
  const int hq = ((bn & 1023) + wc) >> 6;     // head, wave-uniform (wc mult of 64)
  if (bufi < 2) {
    // ---- q/k with fused RoPE: float4 cos/sin from transposed tables ----
    unsigned short* const base = bufi == 0 ? dq : dk;
    const float qsc = bufi == 0 ? 0.180336880f : 1.0f;  // (1/8)*log2(e) for q
    const bool evn = (ln & 1) == 0;
#pragma unroll
    for (int j = 0; j < 4; ++j) {
      int n = bn + wc + j * 16 + ln;
      float bi = bias[n];
      int hd = j * 16 + ln;
      int pi = j * 8 + (ln >> 1);             // == hd>>1
      const float4* c4p = fcT4 + (pi << 10);
      const float4* s4p = fsT4 + (pi << 10);
#pragma unroll
      for (int i = 0; i < 8; ++i) {
        int m0 = bm + wr + i * 16 + quad * 4;  // multiple of 4
        float4 c4 = c4p[m0 >> 2];
        float4 s4 = s4p[m0 >> 2];
        float cs[4] = {c4.x, c4.y, c4.z, c4.w};
        float ss[4] = {s4.x, s4.y, s4.z, s4.w};
#pragma unroll
        for (int r = 0; r < 4; ++r) {
          float val = acc[i][j][r] + bi;
          float par = __shfl_xor(val, 1);
          float o = evn ? (val * cs[r] - par * ss[r]) : (par * ss[r] + val * cs[r]);
          base[((size_t)(hq * S_LEN + (m0 + r))) * HD + hd] = f2b(o * qsc);
        }
      }
    }
  } else {
    // ---- v: write transposed (h,hd,s) via per-wave LDS scratch [64 hd][128 s] ----
    __syncthreads();
    unsigned short* scr =
        (wave < 4 ? (unsigned short*)sA : (unsigned short*)sB) + (wave & 3) * 8192;
#pragma unroll
    for (int i = 0; i < 8; ++i)
#pragma unroll
      for (int j = 0; j < 4; ++j) {
        int n = bn + wc + j * 16 + ln;
        float bi = bias[n];
        int hd = j * 16 + ln;
#pragma unroll
        for (int r = 0; r < 4; ++r) {
          int sl = i * 16 + quad * 4 + r;                     // 0..127 (s-local)
          int byte = hd * 256 + ((((sl >> 3) ^ (hd & 7)) << 4)) + (sl & 7) * 2;
          *(unsigned short*)((char*)scr + byte) = f2b(acc[i][j][r] + bi);
        }
      }
    __syncthreads();
#pragma unroll
    for (int pass = 0; pass < 4; ++pass) {
      int row = pass * 16 + ln;  // hd
      uint4 d[4];
#pragma unroll
      for (int j = 0; j < 4; ++j) {
        int c = quad * 4 + j;  // 16B chunk = 8 s-elements
        d[j] = *(uint4*)((char*)scr + row * 256 + ((c ^ (row & 7)) << 4));
      }
      uint4* dst = (uint4*)(vtout + ((size_t)(hq * HD + row)) * S_LEN + bm + wr + quad * 32);
#pragma unroll
      for (int j = 0; j < 4; ++j) dst[j] = d[j];
    }
  }
}

// ---------------- gemm2: out-proj NT GEMM, 128x64 tile, f32 out -------------------
__global__ __launch_bounds__(256) void gemm_out(
    const unsigned short* __restrict__ A, const unsigned short* __restrict__ B,
    const float* __restrict__ bias, float* __restrict__ outF, int N, int K) {
  __shared__ alignas(16) unsigned short sA[2][128 * 32];
  __shared__ alignas(16) unsigned short sB[2][64 * 32];
  const int tid = threadIdx.x;
  const int lane = tid & 63, wave = tid >> 6;
  const int ln = lane & 15, quad = lane >> 4;
  const int bm = blockIdx.x * 128, bn = blockIdx.y * 64;
  const int wr = (wave >> 1) * 64, wc = (wave & 1) * 32;

  f32x4 acc[4][2];
#pragma unroll
  for (int i = 0; i < 4; ++i)
#pragma unroll
    for (int j = 0; j < 2; ++j) acc[i][j] = fzero4();

  {
#pragma unroll
    for (int i = 0; i < 2; ++i) {
      int o = (i * 256 + tid) * 16;
      int e = o >> 1;
      int row = e >> 5, col = e & 31;
      gload16(A + (size_t)(bm + row) * K + col, (char*)sA[0] + o);
    }
    int o = tid * 16;
    int e = o >> 1;
    int row = e >> 5, col = e & 31;
    gload16(B + (size_t)(bn + row) * K + col, (char*)sB[0] + o);
  }

  int buf = 0;
  for (int k0 = 0; k0 < K; k0 += 32, buf ^= 1) {
    __syncthreads();
    if (k0 + 32 < K) {
#pragma unroll
      for (int i = 0; i < 2; ++i) {
        int o = (i * 256 + tid) * 16;
        int e = o >> 1;
        int row = e >> 5, col = e & 31;
        gload16(A + (size_t)(bm + row) * K + k0 + 32 + col, (char*)sA[buf ^ 1] + o);
      }
      int o = tid * 16;
      int e = o >> 1;
      int row = e >> 5, col = e & 31;
      gload16(B + (size_t)(bn + row) * K + k0 + 32 + col, (char*)sB[buf ^ 1] + o);
    }
    bf16x8 af[4], bfr[2];
#pragma unroll
    for (int i = 0; i < 4; ++i)
      af[i] = *(const bf16x8*)&sA[buf][(wr + i * 16 + ln) * 32 + quad * 8];
#pragma unroll
    for (int j = 0; j < 2; ++j)
      bfr[j] = *(const bf16x8*)&sB[buf][(wc + j * 16 + ln) * 32 + quad * 8];
#pragma unroll
    for (int i = 0; i < 4; ++i)
#pragma unroll
      for (int j = 0; j < 2; ++j)
        acc[i][j] = __builtin_amdgcn_mfma_f32_16x16x32_bf16(af[i], bfr[j], acc[i][j], 0, 0, 0);
  }

#pragma unroll
  for (int i = 0; i < 4; ++i)
#pragma unroll
    for (int j = 0; j < 2; ++j) {
      int n = bn + wc + j * 16 + ln;
      float bi = bias[n];
#pragma unroll
      for (int r = 0; r < 4; ++r) {
        int m = bm + wr + i * 16 + quad * 4 + r;
        outF[(size_t)m * N + n] = acc[i][j][r] + bi;
      }
    }
}

// ---------------- Flash attention, causal, exp2 softmax (no running max) ----------
// R11: 1024 blocks x 512 threads. Block c: head h=c&15 (2 heads/XCD -> KV L2-res),
// q-tile qt=63-(c>>4) heavy-first; group 0 even kv tiles, group 1 odd; merge
// once via LDS. K dbuf (32KB); V single-buffer per parity (16KB) -> 48KB LDS,
// 3 blocks/CU (24 waves/CU), 256-block queue. Per step: vmcnt(0)+barA (K(s)
// landed; sV/sK[buf^1] free) -> issue V(s),K(s+1) -> QK+exp2+pack ->
// vmcnt(2)+barB (V landed, K(s+1) in flight) -> PV. Barriers unconditional.
__global__ __launch_bounds__(512, 6) void flash_kernel(
    const unsigned short* __restrict__ qg, const unsigned short* __restrict__ kg,
    const unsigned short* __restrict__ vtg, unsigned short* __restrict__ attn) {
  __shared__ alignas(16) unsigned short sK[2][2][64 * 64];  // [buf][parity] 32KB
  __shared__ alignas(16) unsigned short sV[2][64 * 64];     // [parity] 16KB

  const int tid = threadIdx.x;
  const int lane = tid & 63, wave = tid >> 6;
  const int w = wave & 3, grp = wave >> 2;   // grp 0: even kv tiles, 1: odd
  const int ln = lane & 15, quad = lane >> 4;
  const int c = blockIdx.x;
  const int h = c & 15;
  const int qt = 63 - (c >> 4);              // q-tile index, big blocks first
  const int qrow = qt * 64 + w * 16;

  const unsigned short* qh = qg + (size_t)h * (S_LEN * HD);
  const unsigned short* kh = kg + (size_t)h * (S_LEN * HD);
  const unsigned short* vh = vtg + (size_t)h * (HD * S_LEN);

  bf16x8 qf[2];
  qf[0] = *(const bf16x8*)(qh + (size_t)(qrow + ln) * HD + quad * 8);
  qf[1] = *(const bf16x8*)(qh + (size_t)(qrow + ln) * HD + 32 + quad * 8);

  f32x4 o_acc[4];
  f32x4 l_acc = fzero4();
#pragma unroll
  for (int t = 0; t < 4; ++t) o_acc[t] = fzero4();
  bf16x8 ones;
#pragma unroll
  for (int j = 0; j < 8; ++j) ones[j] = (short)0x3F80;  // bf16 1.0

  const int nst = (qt + 2) >> 1;             // ceil((qt+1)/2) staged steps
  const int srow = tid >> 3, sch = tid & 7;  // 512 threads: 64 rows x 8 chunks
  const int kswz = (sch ^ (srow & 7)) << 3;  // elem offset, matches lds_swz reads

  // preload K tiles 0 (->[0][0]) and 1 (->[0][1]); tile 1 always in-bounds
  gload16(kh + (size_t)srow * HD + kswz, (char*)sK[0][0] + tid * 16);
  gload16(kh + (size_t)(64 + srow) * HD + kswz, (char*)sK[0][1] + tid * 16);

  // per-step staging pointers (bumped by constant strides)
  const unsigned short* vEp = vh + (size_t)srow * S_LEN + kswz;        // tile 2s
  const unsigned short* vOp = vEp + 64;                                // tile 2s+1
  const unsigned short* kEp = kh + (size_t)(128 + srow) * HD + kswz;   // tile 2s+2
  const unsigned short* kOp = kEp + (size_t)64 * HD;                   // tile 2s+3

  int buf = 0;
  for (int s = 0; s < nst; ++s, buf ^= 1) {
    // ---- barrier A: K(s) landed; PV(s-1)/QK(s-1) reads complete.
    asm volatile("s_waitcnt vmcnt(0)" ::: "memory");
    __builtin_amdgcn_s_barrier();

    // issue V(s) into single buffers, then K(s+1) into sK[buf^1]
    gload16(vEp, (char*)sV[0] + tid * 16);
    gload16(vOp, (char*)sV[1] + tid * 16);
    vEp += 128; vOp += 128;
    const bool pk = (s + 1 < nst);
    if (pk) {
      gload16(kEp, (char*)sK[buf ^ 1][0] + tid * 16);
      gload16(kOp, (char*)sK[buf ^ 1][1] + tid * 16);
      kEp += (size_t)128 * HD; kOp += (size_t)128 * HD;
    }

    const int kt = 2 * s + grp;
    const bool act = (kt <= qt);             // group-1 tail skip when qt even
    bf16x8 pa0, pa1;
    if (act) {
      const unsigned short* kp = sK[buf][grp];
      // S^T = K Q^T: sc[t] holds rows kv-local 16t+quad*4+r, col q-local ln
      f32x4 sc[4];
#pragma unroll
      for (int t = 0; t < 4; ++t) sc[t] = fzero4();
      __builtin_amdgcn_s_setprio(1);
#pragma unroll
      for (int t = 0; t < 4; ++t) {
        bf16x8 kb0 = lds_swz(kp, t * 16 + ln, quad);
        bf16x8 kb1 = lds_swz(kp, t * 16 + ln, 4 + quad);
        sc[t] = __builtin_amdgcn_mfma_f32_16x16x32_bf16(kb0, qf[0], sc[t], 0, 0, 0);
        sc[t] = __builtin_amdgcn_mfma_f32_16x16x32_bf16(kb1, qf[1], sc[t], 0, 0, 0);
      }
      __builtin_amdgcn_s_setprio(0);

      // p = exp2(s); mask only on the diagonal tile (kt == qt)
      float e[4][4];
      if (kt == qt) {
#pragma unroll
        for (int t = 0; t < 4; ++t)
#pragma unroll
          for (int r = 0; r < 4; ++r) {
            int kvl = 16 * t + quad * 4 + r;
            e[t][r] = (kvl <= w * 16 + ln) ? __builtin_amdgcn_exp2f(sc[t][r]) : 0.0f;
          }
      } else {
#pragma unroll
        for (int t = 0; t < 4; ++t)
#pragma unroll
          for (int r = 0; r < 4; ++r) e[t][r] = __builtin_amdgcn_exp2f(sc[t][r]);
      }

      // In-register P -> A-fragment: lane(ln,quad) needs P[q=ln][kv=8*quad+0..7]
      // (pa0) and [32+8*quad+0..7] (pa1).
      unsigned int x0 = pk2t(e[0][0], e[0][1]), x1 = pk2t(e[0][2], e[0][3]);
      unsigned int y0 = pk2t(e[1][0], e[1][1]), y1 = pk2t(e[1][2], e[1][3]);
      unsigned int z0 = pk2t(e[2][0], e[2][1]), z1 = pk2t(e[2][2], e[2][3]);
      unsigned int w0 = pk2t(e[3][0], e[3][1]), w1 = pk2t(e[3][2], e[3][3]);
      auto a32 = __builtin_amdgcn_permlane32_swap(x0, y0, false, false);
      auto a16 = __builtin_amdgcn_permlane16_swap(a32[0], a32[1], false, false);
      auto b32 = __builtin_amdgcn_permlane32_swap(x1, y1, false, false);
      auto b16 = __builtin_amdgcn_permlane16_swap(b32[0], b32[1], false, false);
      auto c32 = __builtin_amdgcn_permlane32_swap(z0, w0, false, false);
      auto c16 = __builtin_amdgcn_permlane16_swap(c32[0], c32[1], false, false);
      auto d32 = __builtin_amdgcn_permlane32_swap(z1, w1, false, false);
      auto d16 = __builtin_amdgcn_permlane16_swap(d32[0], d32[1], false, false);
      union { uint4 u; bf16x8 b; } pa0u, pa1u;
      pa0u.u = make_uint4(a16[0], b16[0], a16[1], b16[1]);
      pa1u.u = make_uint4(c16[0], d16[0], c16[1], d16[1]);
      pa0 = pa0u.b; pa1 = pa1u.b;
    }

    // ---- barrier B: every wave's V(s) loads drained (K(s+1) stays in flight)
    if (pk) asm volatile("s_waitcnt vmcnt(2)" ::: "memory");
    else    asm volatile("s_waitcnt vmcnt(0)" ::: "memory");
    __builtin_amdgcn_s_barrier();

    if (act) {
      const unsigned short* vp = sV[grp];
      // l += P @ ones; O += P @ V
      __builtin_amdgcn_s_setprio(1);
      l_acc = __builtin_amdgcn_mfma_f32_16x16x32_bf16(pa0, ones, l_acc, 0, 0, 0);
      l_acc = __builtin_amdgcn_mfma_f32_16x16x32_bf16(pa1, ones, l_acc, 0, 0, 0);
#pragma unroll
      for (int t = 0; t < 4; ++t) {
        bf16x8 vb0 = lds_swz(vp, t * 16 + ln, quad);
        bf16x8 vb1 = lds_swz(vp, t * 16 + ln, 4 + quad);
        o_acc[t] = __builtin_amdgcn_mfma_f32_16x16x32_bf16(pa0, vb0, o_acc[t], 0, 0, 0);
        o_acc[t] = __builtin_amdgcn_mfma_f32_16x16x32_bf16(pa1, vb1, o_acc[t], 0, 0, 0);
      }
      __builtin_amdgcn_s_setprio(0);
    }
  }

  // merge group 1's partial (O,l) into group 0 via LDS (reuse sK), then epilogue
  __syncthreads();  // all compute done; no DMA in flight
  float* mrg = (float*)sK;
  const int mi = (w * 64 + lane) * 20;  // 20 f32/lane, 16B-aligned blob
  if (grp == 1) {
    *(f32x4*)&mrg[mi +  0] = o_acc[0];
    *(f32x4*)&mrg[mi +  4] = o_acc[1];
    *(f32x4*)&mrg[mi +  8] = o_acc[2];
    *(f32x4*)&mrg[mi + 12] = o_acc[3];
    *(f32x4*)&mrg[mi + 16] = l_acc;
  }
  __syncthreads();
  if (grp == 0) {
    o_acc[0] += *(const f32x4*)&mrg[mi + 0];
    o_acc[1] += *(const f32x4*)&mrg[mi + 4];
    o_acc[2] += *(const f32x4*)&mrg[mi + 8];
    o_acc[3] += *(const f32x4*)&mrg[mi + 12];
    l_acc += *(const f32x4*)&mrg[mi + 16];
    float inv[4];
#pragma unroll
    for (int r = 0; r < 4; ++r) inv[r] = 1.0f / l_acc[r];
#pragma unroll
    for (int t = 0; t < 4; ++t)
#pragma unroll
      for (int r = 0; r < 4; ++r) {
        int row = qrow + quad * 4 + r;
        attn[(size_t)row * DIM + h * HD + t * 16 + ln] = f2b(o_acc[t][r] * inv[r]);
      }
  }
}

extern "C" void kernel_launch(void* const* d_in, const int* in_sizes, int n_in,
                              void* d_out, int out_size, void* d_ws, size_t ws_size,
                              hipStream_t stream) {
  const float* x    = (const float*)d_in[0];
  const float* fc   = (const float*)d_in[2];
  const float* fs   = (const float*)d_in[3];
  const float* wqw  = (const float*)d_in[5];
  const float* wqb  = (const float*)d_in[6];
  const float* wkw  = (const float*)d_in[7];
  const float* wkb  = (const float*)d_in[8];
  const float* wvw  = (const float*)d_in[9];
  const float* wvb  = (const float*)d_in[10];
  const float* wow  = (const float*)d_in[11];
  const float* wobf = (const float*)d_in[12];
  float* out = (float*)d_out;

  char* ws = (char*)d_ws;
  const size_t MB = (size_t)1 << 20;
  const size_t KB = (size_t)1 << 10;
  unsigned short* xb    = (unsigned short*)(ws + 0);
  unsigned short* wqkvb = (unsigned short*)(ws + 8 * MB);
  unsigned short* wobb  = (unsigned short*)(ws + 16 * MB);
  float* biasq = (float*)(ws + 18 * MB);
  float* biaso = (float*)(ws + 18 * MB + 64 * KB);
  float4* fcT4 = (float4*)(ws + 18 * MB + 128 * KB);   // 512KB, [32][4096] f32
  float4* fsT4 = (float4*)(ws + 18 * MB + 640 * KB);   // 512KB
  unsigned short* qb_ = (unsigned short*)(ws + 19 * MB);
  unsigned short* kb_ = (unsigned short*)(ws + 27 * MB);
  unsigned short* vt  = (unsigned short*)(ws + 35 * MB);  // vT written by gemm1
  unsigned short* attn = (unsigned short*)(ws + 0);       // aliases xb (dead after gemm1)

  cvt_all<<<8452, 256, 0, stream>>>(x, wqw, wkw, wvw, wow, wqb, wkb, wvb, wobf,
                                    fc, fs, xb, wqkvb, wobb, biasq, biaso, fcT4, fsT4);
  gemm_qkv<<<dim3(16, 12), 512, 0, stream>>>(xb, wqkvb, biasq, qb_, kb_, vt, fcT4, fsT4, 1024);
  flash_kernel<<<1024, 512, 0, stream>>>(qb_, kb_, vt, attn);
  gemm_out<<<dim3(32, 16), 256, 0, stream>>>(attn, wobb, biaso, out, 1024, 1024);
}

// Round 13
// 244.666 us; speedup vs baseline: 1.0044x; 1.0044x over previous
//
#include <hip/hip_runtime.h>

// AttentionLoRA: B=1, S=4096, D=1024, H=16, HD=64.
// Pipeline (4 kernels):
//   cvt_all (f32->bf16 + bias pack + RoPE table transpose fcT/fsT[32][4096])
//   gemm1: QKV NT-GEMM, 256x256 tile / BK=64 / 8 waves / 128KB dbuf LDS,
//          8-phase schedule with counted vmcnt (T3+T4), both-sides LDS swizzle.
//          Epilogue fuses RoPE (q/k; float4 loads from transposed tables) and
//          V-transpose -> vT (h,hd,s).
//   flash: R11 (proven): 1024 blocks x 512 thr, even/odd kv parity groups,
//          heavy-first queue; K dbuf 32KB + V single-buffer 16KB = 48KB LDS ->
//          3 blocks/CU (24 waves/CU) with 256-block queue; split-phase sync
//          {vmcnt0;barA; issue V(s),K(s+1); QK+exp2+pack; vmcnt;barB; PV}.
//   gemm2: out-proj, 128x64 tiles (512 blocks, 2/CU), f32 out.
// R13 FIX: R12's fsT4 (18MB+640KB..+1152KB) overlapped qb_ (19MB) by 128KB --
// gemm_qkv q-writes raced RoPE sin reads (absmax 0.0078->0.0234, near the
// 0.0244 threshold). qb_/kb_/vt shifted +256KB; no kernel code changes.
// Session rules: grid must exceed residency slots (R6/R8); MFMA B-fragments
// direct from global are per-lane row-scattered -> LDS-stage them (R9).

#define S_LEN 4096
#define DIM   1024
#define NH    16
#define HD    64

typedef __attribute__((ext_vector_type(8))) short bf16x8;   // 8 bf16 = 4 VGPRs
typedef __attribute__((ext_vector_type(4))) float f32x4;

__device__ __forceinline__ unsigned short f2b(float f) {
  union { float f; unsigned int u; } v; v.f = f;
  unsigned int r = (v.u + 0x7fffu + ((v.u >> 16) & 1u)) >> 16;  // RNE
  return (unsigned short)r;
}
__device__ __forceinline__ float b2f(unsigned short h) {
  union { unsigned int u; float f; } v; v.u = ((unsigned int)h) << 16;
  return v.f;
}
// pack two f32 -> two bf16 by truncation (p in [0,1]; <=1ulp)
__device__ __forceinline__ unsigned int pk2t(float a, float b) {
  union { float f; unsigned int u; } x, y; x.f = a; y.f = b;
  return (x.u >> 16) | (y.u & 0xffff0000u);
}
__device__ __forceinline__ void gload16(const void* g, void* l) {
  __builtin_amdgcn_global_load_lds(
      (const __attribute__((address_space(1))) unsigned int*)g,
      (__attribute__((address_space(3))) unsigned int*)l, 16, 0, 0);
}
__device__ __forceinline__ f32x4 fzero4() { f32x4 z = {0.f, 0.f, 0.f, 0.f}; return z; }

// ---- LDS swizzled 16B read: row-major [rows][128B], chunk XOR row&7 -------------
__device__ __forceinline__ bf16x8 lds_swz(const unsigned short* s, int row, int chunk) {
  int byte = row * 128 + ((chunk ^ (row & 7)) << 4);
  return *(const bf16x8*)((const char*)s + byte);
}

// ---------------- fused f32->bf16 convert + bias pack + RoPE table transpose ------
__global__ void cvt_all(const float* __restrict__ x, const float* __restrict__ wq,
                        const float* __restrict__ wk, const float* __restrict__ wv,
                        const float* __restrict__ wo, const float* __restrict__ qb,
                        const float* __restrict__ kb, const float* __restrict__ vbs,
                        const float* __restrict__ ob, const float* __restrict__ fc,
                        const float* __restrict__ fs, unsigned short* __restrict__ xb,
                        unsigned short* __restrict__ wqkvb, unsigned short* __restrict__ wobb,
                        float* __restrict__ biasq, float* __restrict__ biaso,
                        float4* __restrict__ fcT4, float4* __restrict__ fsT4) {
  int i = blockIdx.x * 256 + threadIdx.x;  // float4 index
  if (i < 2097152) {
    const float* src; unsigned short* dst; int off;
    if (i < 1048576)      { src = x;  dst = xb;              off = i; }
    else if (i < 1310720) { src = wq; dst = wqkvb;           off = i - 1048576; }
    else if (i < 1572864) { src = wk; dst = wqkvb + 1048576; off = i - 1310720; }
    else if (i < 1835008) { src = wv; dst = wqkvb + 2097152; off = i - 1572864; }
    else                  { src = wo; dst = wobb;            off = i - 1835008; }
    float4 v = ((const float4*)src)[off];
    unsigned int lo = (unsigned int)f2b(v.x) | ((unsigned int)f2b(v.y) << 16);
    unsigned int hi = (unsigned int)f2b(v.z) | ((unsigned int)f2b(v.w) << 16);
    ((uint2*)dst)[off] = make_uint2(lo, hi);
  } else if (i < 2097152 + 1024) {
    int j = i - 2097152;
    if (j < 256)      ((float4*)biasq)[j]              = ((const float4*)qb)[j];
    else if (j < 512) ((float4*)(biasq + 1024))[j-256] = ((const float4*)kb)[j-256];
    else if (j < 768) ((float4*)(biasq + 2048))[j-512] = ((const float4*)vbs)[j-512];
    else              ((float4*)biaso)[j-768]          = ((const float4*)ob)[j-768];
  } else if (i < 2098176 + 65536) {
    // transpose fc/fs (S,32) -> fcT/fsT [32][4096] as float4 over m
    int j = i - 2098176;
    const float* src = (j < 32768) ? fc : fs;
    float4* dst = (j < 32768) ? fcT4 : fsT4;
    int jj = j & 32767;
    int pi = jj >> 10, m0 = (jj & 1023) << 2;
    float4 v;
    v.x = src[(m0 + 0) * 32 + pi];
    v.y = src[(m0 + 1) * 32 + pi];
    v.z = src[(m0 + 2) * 32 + pi];
    v.w = src[(m0 + 3) * 32 + pi];
    dst[jj] = v;
  }
}

// ---------------- gemm1: QKV NT-GEMM, 256x256/BK=64, 8-phase counted-vmcnt --------
__global__ __launch_bounds__(512, 2) void gemm_qkv(
    const unsigned short* __restrict__ A, const unsigned short* __restrict__ B,
    const float* __restrict__ bias, unsigned short* __restrict__ dq,
    unsigned short* __restrict__ dk, unsigned short* __restrict__ vtout,
    const float4* __restrict__ fcT4, const float4* __restrict__ fsT4, int K) {
  __shared__ alignas(16) unsigned short sA[2][256 * 64];  // 64KB
  __shared__ alignas(16) unsigned short sB[2][256 * 64];  // 64KB
  const int tid = threadIdx.x;
  const int lane = tid & 63, wave = tid >> 6;
  const int ln = lane & 15, quad = lane >> 4;
  const int bm = blockIdx.x * 256, bn = blockIdx.y * 256;
  const int wr = (wave >> 2) * 128, wc = (wave & 3) * 64;
  const int NT = K >> 6;  // 16 K-tiles

  f32x4 acc[8][4];
#pragma unroll
  for (int i = 0; i < 8; ++i)
#pragma unroll
    for (int j = 0; j < 4; ++j) acc[i][j] = fzero4();

#define STAGE(tt, ch) do {                                                   \
    int o_ = ((ch) * 512 + tid) * 8;                                         \
    int row_ = o_ >> 6, c_ = (o_ >> 3) & 7;                                  \
    int col_ = ((tt) << 6) + ((c_ ^ (row_ & 7)) << 3);                       \
    int bs_ = (tt) & 1;                                                      \
    gload16(A + (size_t)(bm + row_) * K + col_, (char*)sA[bs_] + o_ * 2);    \
    gload16(B + (size_t)(bn + row_) * K + col_, (char*)sB[bs_] + o_ * 2);    \
  } while (0)
#define BAR()   __builtin_amdgcn_s_barrier()
#define LGKM0() asm volatile("s_waitcnt lgkmcnt(0)" ::: "memory")

  STAGE(0, 0); STAGE(0, 1); STAGE(0, 2); STAGE(0, 3); STAGE(1, 0);
  asm volatile("s_waitcnt vmcnt(2)" ::: "memory");
  BAR();

#pragma unroll 2
  for (int t = 0; t < 16; ++t) {
    const unsigned short* cA = sA[t & 1];
    const unsigned short* cB = sB[t & 1];
    bf16x8 a0[4], a1[4], b0[4], b1[4];

    // ---- phase 0
#pragma unroll
    for (int j = 0; j < 4; ++j) b0[j] = lds_swz(cB, wc + j * 16 + ln, quad);
#pragma unroll
    for (int i = 0; i < 4; ++i) a0[i] = lds_swz(cA, wr + i * 16 + ln, quad);
    if (t + 1 < NT) STAGE(t + 1, 1);
    BAR(); LGKM0();
    __builtin_amdgcn_s_setprio(1);
#pragma unroll
    for (int i = 0; i < 4; ++i)
#pragma unroll
      for (int j = 0; j < 4; ++j)
        acc[i][j] = __builtin_amdgcn_mfma_f32_16x16x32_bf16(a0[i], b0[j], acc[i][j], 0, 0, 0);
    __builtin_amdgcn_s_setprio(0);
    BAR();

    // ---- phase 1
#pragma unroll
    for (int i = 0; i < 4; ++i) a1[i] = lds_swz(cA, wr + (i + 4) * 16 + ln, quad);
#pragma unroll
    for (int j = 0; j < 4; ++j) b1[j] = lds_swz(cB, wc + j * 16 + ln, 4 + quad);
    if (t + 1 < NT) STAGE(t + 1, 2);
    BAR(); LGKM0();
    __builtin_amdgcn_s_setprio(1);
#pragma unroll
    for (int i = 0; i < 4; ++i)
#pragma unroll
      for (int j = 0; j < 4; ++j)
        acc[i + 4][j] = __builtin_amdgcn_mfma_f32_16x16x32_bf16(a1[i], b0[j], acc[i + 4][j], 0, 0, 0);
    __builtin_amdgcn_s_setprio(0);
    BAR();

    // ---- phase 2
#pragma unroll
    for (int i = 0; i < 4; ++i) a0[i] = lds_swz(cA, wr + i * 16 + ln, 4 + quad);
#pragma unroll
    for (int i = 0; i < 4; ++i) a1[i] = lds_swz(cA, wr + (i + 4) * 16 + ln, 4 + quad);
    if (t + 1 < NT) STAGE(t + 1, 3);
    BAR(); LGKM0();
    __builtin_amdgcn_s_setprio(1);
#pragma unroll
    for (int i = 0; i < 4; ++i)
#pragma unroll
      for (int j = 0; j < 4; ++j)
        acc[i][j] = __builtin_amdgcn_mfma_f32_16x16x32_bf16(a0[i], b1[j], acc[i][j], 0, 0, 0);
    __builtin_amdgcn_s_setprio(0);
    BAR();

    // ---- phase 3
    if (t + 2 < NT) STAGE(t + 2, 0);
    BAR(); LGKM0();
    __builtin_amdgcn_s_setprio(1);
#pragma unroll
    for (int i = 0; i < 4; ++i)
#pragma unroll
      for (int j = 0; j < 4; ++j)
        acc[i + 4][j] = __builtin_amdgcn_mfma_f32_16x16x32_bf16(a1[i], b1[j], acc[i + 4][j], 0, 0, 0);
    __builtin_amdgcn_s_setprio(0);
    if (t < 14) {
      asm volatile("s_waitcnt vmcnt(2)" ::: "memory");
      BAR();
    } else if (t == 14) {
      asm volatile("s_waitcnt vmcnt(0)" ::: "memory");
      BAR();
    }
  }
#undef STAGE
#undef BAR
#undef LGKM0

  const int bufi = bn >> 10;                  // 0:q 1:k 2:v (block-uniform)
  const int hq = ((bn & 1023) + wc) >> 6;     // head, wave-uniform (wc mult of 64)
  if (bufi < 2) {
    // ---- q/k with fused RoPE: float4 cos/sin from transposed tables ----
    unsigned short* const base = bufi == 0 ? dq : dk;
    const float qsc = bufi == 0 ? 0.180336880f : 1.0f;  // (1/8)*log2(e) for q
    const bool evn = (ln & 1) == 0;
#pragma unroll
    for (int j = 0; j < 4; ++j) {
      int n = bn + wc + j * 16 + ln;
      float bi = bias[n];
      int hd = j * 16 + ln;
      int pi = j * 8 + (ln >> 1);             // == hd>>1
      const float4* c4p = fcT4 + (pi << 10);
      const float4* s4p = fsT4 + (pi << 10);
#pragma unroll
      for (int i = 0; i < 8; ++i) {
        int m0 = bm + wr + i * 16 + quad * 4;  // multiple of 4
        float4 c4 = c4p[m0 >> 2];
        float4 s4 = s4p[m0 >> 2];
        float cs[4] = {c4.x, c4.y, c4.z, c4.w};
        float ss[4] = {s4.x, s4.y, s4.z, s4.w};
#pragma unroll
        for (int r = 0; r < 4; ++r) {
          float val = acc[i][j][r] + bi;
          float par = __shfl_xor(val, 1);
          float o = evn ? (val * cs[r] - par * ss[r]) : (par * ss[r] + val * cs[r]);
          base[((size_t)(hq * S_LEN + (m0 + r))) * HD + hd] = f2b(o * qsc);
        }
      }
    }
  } else {
    // ---- v: write transposed (h,hd,s) via per-wave LDS scratch [64 hd][128 s] ----
    __syncthreads();
    unsigned short* scr =
        (wave < 4 ? (unsigned short*)sA : (unsigned short*)sB) + (wave & 3) * 8192;
#pragma unroll
    for (int i = 0; i < 8; ++i)
#pragma unroll
      for (int j = 0; j < 4; ++j) {
        int n = bn + wc + j * 16 + ln;
        float bi = bias[n];
        int hd = j * 16 + ln;
#pragma unroll
        for (int r = 0; r < 4; ++r) {
          int sl = i * 16 + quad * 4 + r;                     // 0..127 (s-local)
          int byte = hd * 256 + ((((sl >> 3) ^ (hd & 7)) << 4)) + (sl & 7) * 2;
          *(unsigned short*)((char*)scr + byte) = f2b(acc[i][j][r] + bi);
        }
      }
    __syncthreads();
#pragma unroll
    for (int pass = 0; pass < 4; ++pass) {
      int row = pass * 16 + ln;  // hd
      uint4 d[4];
#pragma unroll
      for (int j = 0; j < 4; ++j) {
        int c = quad * 4 + j;  // 16B chunk = 8 s-elements
        d[j] = *(uint4*)((char*)scr + row * 256 + ((c ^ (row & 7)) << 4));
      }
      uint4* dst = (uint4*)(vtout + ((size_t)(hq * HD + row)) * S_LEN + bm + wr + quad * 32);
#pragma unroll
      for (int j = 0; j < 4; ++j) dst[j] = d[j];
    }
  }
}

// ---------------- gemm2: out-proj NT GEMM, 128x64 tile, f32 out -------------------
__global__ __launch_bounds__(256) void gemm_out(
    const unsigned short* __restrict__ A, const unsigned short* __restrict__ B,
    const float* __restrict__ bias, float* __restrict__ outF, int N, int K) {
  __shared__ alignas(16) unsigned short sA[2][128 * 32];
  __shared__ alignas(16) unsigned short sB[2][64 * 32];
  const int tid = threadIdx.x;
  const int lane = tid & 63, wave = tid >> 6;
  const int ln = lane & 15, quad = lane >> 4;
  const int bm = blockIdx.x * 128, bn = blockIdx.y * 64;
  const int wr = (wave >> 1) * 64, wc = (wave & 1) * 32;

  f32x4 acc[4][2];
#pragma unroll
  for (int i = 0; i < 4; ++i)
#pragma unroll
    for (int j = 0; j < 2; ++j) acc[i][j] = fzero4();

  {
#pragma unroll
    for (int i = 0; i < 2; ++i) {
      int o = (i * 256 + tid) * 16;
      int e = o >> 1;
      int row = e >> 5, col = e & 31;
      gload16(A + (size_t)(bm + row) * K + col, (char*)sA[0] + o);
    }
    int o = tid * 16;
    int e = o >> 1;
    int row = e >> 5, col = e & 31;
    gload16(B + (size_t)(bn + row) * K + col, (char*)sB[0] + o);
  }

  int buf = 0;
  for (int k0 = 0; k0 < K; k0 += 32, buf ^= 1) {
    __syncthreads();
    if (k0 + 32 < K) {
#pragma unroll
      for (int i = 0; i < 2; ++i) {
        int o = (i * 256 + tid) * 16;
        int e = o >> 1;
        int row = e >> 5, col = e & 31;
        gload16(A + (size_t)(bm + row) * K + k0 + 32 + col, (char*)sA[buf ^ 1] + o);
      }
      int o = tid * 16;
      int e = o >> 1;
      int row = e >> 5, col = e & 31;
      gload16(B + (size_t)(bn + row) * K + k0 + 32 + col, (char*)sB[buf ^ 1] + o);
    }
    bf16x8 af[4], bfr[2];
#pragma unroll
    for (int i = 0; i < 4; ++i)
      af[i] = *(const bf16x8*)&sA[buf][(wr + i * 16 + ln) * 32 + quad * 8];
#pragma unroll
    for (int j = 0; j < 2; ++j)
      bfr[j] = *(const bf16x8*)&sB[buf][(wc + j * 16 + ln) * 32 + quad * 8];
#pragma unroll
    for (int i = 0; i < 4; ++i)
#pragma unroll
      for (int j = 0; j < 2; ++j)
        acc[i][j] = __builtin_amdgcn_mfma_f32_16x16x32_bf16(af[i], bfr[j], acc[i][j], 0, 0, 0);
  }

#pragma unroll
  for (int i = 0; i < 4; ++i)
#pragma unroll
    for (int j = 0; j < 2; ++j) {
      int n = bn + wc + j * 16 + ln;
      float bi = bias[n];
#pragma unroll
      for (int r = 0; r < 4; ++r) {
        int m = bm + wr + i * 16 + quad * 4 + r;
        outF[(size_t)m * N + n] = acc[i][j][r] + bi;
      }
    }
}

// ---------------- Flash attention, causal, exp2 softmax (no running max) ----------
// R11: 1024 blocks x 512 threads. Block c: head h=c&15 (2 heads/XCD -> KV L2-res),
// q-tile qt=63-(c>>4) heavy-first; group 0 even kv tiles, group 1 odd; merge
// once via LDS. K dbuf (32KB); V single-buffer per parity (16KB) -> 48KB LDS,
// 3 blocks/CU (24 waves/CU), 256-block queue. Per step: vmcnt(0)+barA (K(s)
// landed; sV/sK[buf^1] free) -> issue V(s),K(s+1) -> QK+exp2+pack ->
// vmcnt(2)+barB (V landed, K(s+1) in flight) -> PV. Barriers unconditional.
__global__ __launch_bounds__(512, 6) void flash_kernel(
    const unsigned short* __restrict__ qg, const unsigned short* __restrict__ kg,
    const unsigned short* __restrict__ vtg, unsigned short* __restrict__ attn) {
  __shared__ alignas(16) unsigned short sK[2][2][64 * 64];  // [buf][parity] 32KB
  __shared__ alignas(16) unsigned short sV[2][64 * 64];     // [parity] 16KB

  const int tid = threadIdx.x;
  const int lane = tid & 63, wave = tid >> 6;
  const int w = wave & 3, grp = wave >> 2;   // grp 0: even kv tiles, 1: odd
  const int ln = lane & 15, quad = lane >> 4;
  const int c = blockIdx.x;
  const int h = c & 15;
  const int qt = 63 - (c >> 4);              // q-tile index, big blocks first
  const int qrow = qt * 64 + w * 16;

  const unsigned short* qh = qg + (size_t)h * (S_LEN * HD);
  const unsigned short* kh = kg + (size_t)h * (S_LEN * HD);
  const unsigned short* vh = vtg + (size_t)h * (HD * S_LEN);

  bf16x8 qf[2];
  qf[0] = *(const bf16x8*)(qh + (size_t)(qrow + ln) * HD + quad * 8);
  qf[1] = *(const bf16x8*)(qh + (size_t)(qrow + ln) * HD + 32 + quad * 8);

  f32x4 o_acc[4];
  f32x4 l_acc = fzero4();
#pragma unroll
  for (int t = 0; t < 4; ++t) o_acc[t] = fzero4();
  bf16x8 ones;
#pragma unroll
  for (int j = 0; j < 8; ++j) ones[j] = (short)0x3F80;  // bf16 1.0

  const int nst = (qt + 2) >> 1;             // ceil((qt+1)/2) staged steps
  const int srow = tid >> 3, sch = tid & 7;  // 512 threads: 64 rows x 8 chunks
  const int kswz = (sch ^ (srow & 7)) << 3;  // elem offset, matches lds_swz reads

  // preload K tiles 0 (->[0][0]) and 1 (->[0][1]); tile 1 always in-bounds
  gload16(kh + (size_t)srow * HD + kswz, (char*)sK[0][0] + tid * 16);
  gload16(kh + (size_t)(64 + srow) * HD + kswz, (char*)sK[0][1] + tid * 16);

  // per-step staging pointers (bumped by constant strides)
  const unsigned short* vEp = vh + (size_t)srow * S_LEN + kswz;        // tile 2s
  const unsigned short* vOp = vEp + 64;                                // tile 2s+1
  const unsigned short* kEp = kh + (size_t)(128 + srow) * HD + kswz;   // tile 2s+2
  const unsigned short* kOp = kEp + (size_t)64 * HD;                   // tile 2s+3

  int buf = 0;
  for (int s = 0; s < nst; ++s, buf ^= 1) {
    // ---- barrier A: K(s) landed; PV(s-1)/QK(s-1) reads complete.
    asm volatile("s_waitcnt vmcnt(0)" ::: "memory");
    __builtin_amdgcn_s_barrier();

    // issue V(s) into single buffers, then K(s+1) into sK[buf^1]
    gload16(vEp, (char*)sV[0] + tid * 16);
    gload16(vOp, (char*)sV[1] + tid * 16);
    vEp += 128; vOp += 128;
    const bool pk = (s + 1 < nst);
    if (pk) {
      gload16(kEp, (char*)sK[buf ^ 1][0] + tid * 16);
      gload16(kOp, (char*)sK[buf ^ 1][1] + tid * 16);
      kEp += (size_t)128 * HD; kOp += (size_t)128 * HD;
    }

    const int kt = 2 * s + grp;
    const bool act = (kt <= qt);             // group-1 tail skip when qt even
    bf16x8 pa0, pa1;
    if (act) {
      const unsigned short* kp = sK[buf][grp];
      // S^T = K Q^T: sc[t] holds rows kv-local 16t+quad*4+r, col q-local ln
      f32x4 sc[4];
#pragma unroll
      for (int t = 0; t < 4; ++t) sc[t] = fzero4();
      __builtin_amdgcn_s_setprio(1);
#pragma unroll
      for (int t = 0; t < 4; ++t) {
        bf16x8 kb0 = lds_swz(kp, t * 16 + ln, quad);
        bf16x8 kb1 = lds_swz(kp, t * 16 + ln, 4 + quad);
        sc[t] = __builtin_amdgcn_mfma_f32_16x16x32_bf16(kb0, qf[0], sc[t], 0, 0, 0);
        sc[t] = __builtin_amdgcn_mfma_f32_16x16x32_bf16(kb1, qf[1], sc[t], 0, 0, 0);
      }
      __builtin_amdgcn_s_setprio(0);

      // p = exp2(s); mask only on the diagonal tile (kt == qt)
      float e[4][4];
      if (kt == qt) {
#pragma unroll
        for (int t = 0; t < 4; ++t)
#pragma unroll
          for (int r = 0; r < 4; ++r) {
            int kvl = 16 * t + quad * 4 + r;
            e[t][r] = (kvl <= w * 16 + ln) ? __builtin_amdgcn_exp2f(sc[t][r]) : 0.0f;
          }
      } else {
#pragma unroll
        for (int t = 0; t < 4; ++t)
#pragma unroll
          for (int r = 0; r < 4; ++r) e[t][r] = __builtin_amdgcn_exp2f(sc[t][r]);
      }

      // In-register P -> A-fragment: lane(ln,quad) needs P[q=ln][kv=8*quad+0..7]
      // (pa0) and [32+8*quad+0..7] (pa1).
      unsigned int x0 = pk2t(e[0][0], e[0][1]), x1 = pk2t(e[0][2], e[0][3]);
      unsigned int y0 = pk2t(e[1][0], e[1][1]), y1 = pk2t(e[1][2], e[1][3]);
      unsigned int z0 = pk2t(e[2][0], e[2][1]), z1 = pk2t(e[2][2], e[2][3]);
      unsigned int w0 = pk2t(e[3][0], e[3][1]), w1 = pk2t(e[3][2], e[3][3]);
      auto a32 = __builtin_amdgcn_permlane32_swap(x0, y0, false, false);
      auto a16 = __builtin_amdgcn_permlane16_swap(a32[0], a32[1], false, false);
      auto b32 = __builtin_amdgcn_permlane32_swap(x1, y1, false, false);
      auto b16 = __builtin_amdgcn_permlane16_swap(b32[0], b32[1], false, false);
      auto c32 = __builtin_amdgcn_permlane32_swap(z0, w0, false, false);
      auto c16 = __builtin_amdgcn_permlane16_swap(c32[0], c32[1], false, false);
      auto d32 = __builtin_amdgcn_permlane32_swap(z1, w1, false, false);
      auto d16 = __builtin_amdgcn_permlane16_swap(d32[0], d32[1], false, false);
      union { uint4 u; bf16x8 b; } pa0u, pa1u;
      pa0u.u = make_uint4(a16[0], b16[0], a16[1], b16[1]);
      pa1u.u = make_uint4(c16[0], d16[0], c16[1], d16[1]);
      pa0 = pa0u.b; pa1 = pa1u.b;
    }

    // ---- barrier B: every wave's V(s) loads drained (K(s+1) stays in flight)
    if (pk) asm volatile("s_waitcnt vmcnt(2)" ::: "memory");
    else    asm volatile("s_waitcnt vmcnt(0)" ::: "memory");
    __builtin_amdgcn_s_barrier();

    if (act) {
      const unsigned short* vp = sV[grp];
      // l += P @ ones; O += P @ V
      __builtin_amdgcn_s_setprio(1);
      l_acc = __builtin_amdgcn_mfma_f32_16x16x32_bf16(pa0, ones, l_acc, 0, 0, 0);
      l_acc = __builtin_amdgcn_mfma_f32_16x16x32_bf16(pa1, ones, l_acc, 0, 0, 0);
#pragma unroll
      for (int t = 0; t < 4; ++t) {
        bf16x8 vb0 = lds_swz(vp, t * 16 + ln, quad);
        bf16x8 vb1 = lds_swz(vp, t * 16 + ln, 4 + quad);
        o_acc[t] = __builtin_amdgcn_mfma_f32_16x16x32_bf16(pa0, vb0, o_acc[t], 0, 0, 0);
        o_acc[t] = __builtin_amdgcn_mfma_f32_16x16x32_bf16(pa1, vb1, o_acc[t], 0, 0, 0);
      }
      __builtin_amdgcn_s_setprio(0);
    }
  }

  // merge group 1's partial (O,l) into group 0 via LDS (reuse sK), then epilogue
  __syncthreads();  // all compute done; no DMA in flight
  float* mrg = (float*)sK;
  const int mi = (w * 64 + lane) * 20;  // 20 f32/lane, 16B-aligned blob
  if (grp == 1) {
    *(f32x4*)&mrg[mi +  0] = o_acc[0];
    *(f32x4*)&mrg[mi +  4] = o_acc[1];
    *(f32x4*)&mrg[mi +  8] = o_acc[2];
    *(f32x4*)&mrg[mi + 12] = o_acc[3];
    *(f32x4*)&mrg[mi + 16] = l_acc;
  }
  __syncthreads();
  if (grp == 0) {
    o_acc[0] += *(const f32x4*)&mrg[mi + 0];
    o_acc[1] += *(const f32x4*)&mrg[mi + 4];
    o_acc[2] += *(const f32x4*)&mrg[mi + 8];
    o_acc[3] += *(const f32x4*)&mrg[mi + 12];
    l_acc += *(const f32x4*)&mrg[mi + 16];
    float inv[4];
#pragma unroll
    for (int r = 0; r < 4; ++r) inv[r] = 1.0f / l_acc[r];
#pragma unroll
    for (int t = 0; t < 4; ++t)
#pragma unroll
      for (int r = 0; r < 4; ++r) {
        int row = qrow + quad * 4 + r;
        attn[(size_t)row * DIM + h * HD + t * 16 + ln] = f2b(o_acc[t][r] * inv[r]);
      }
  }
}

extern "C" void kernel_launch(void* const* d_in, const int* in_sizes, int n_in,
                              void* d_out, int out_size, void* d_ws, size_t ws_size,
                              hipStream_t stream) {
  const float* x    = (const float*)d_in[0];
  const float* fc   = (const float*)d_in[2];
  const float* fs   = (const float*)d_in[3];
  const float* wqw  = (const float*)d_in[5];
  const float* wqb  = (const float*)d_in[6];
  const float* wkw  = (const float*)d_in[7];
  const float* wkb  = (const float*)d_in[8];
  const float* wvw  = (const float*)d_in[9];
  const float* wvb  = (const float*)d_in[10];
  const float* wow  = (const float*)d_in[11];
  const float* wobf = (const float*)d_in[12];
  float* out = (float*)d_out;

  char* ws = (char*)d_ws;
  const size_t MB = (size_t)1 << 20;
  const size_t KB = (size_t)1 << 10;
  unsigned short* xb    = (unsigned short*)(ws + 0);
  unsigned short* wqkvb = (unsigned short*)(ws + 8 * MB);
  unsigned short* wobb  = (unsigned short*)(ws + 16 * MB);
  float* biasq = (float*)(ws + 18 * MB);
  float* biaso = (float*)(ws + 18 * MB + 64 * KB);
  float4* fcT4 = (float4*)(ws + 18 * MB + 128 * KB);   // 512KB, [32][4096] f32
  float4* fsT4 = (float4*)(ws + 18 * MB + 640 * KB);   // 512KB, ends 19MB+128KB
  // R13: qb_/kb_/vt shifted +256KB so qb_ clears fsT4's end (R12 overlapped by
  // 128KB -> gemm_qkv q-writes raced RoPE sin reads).
  unsigned short* qb_ = (unsigned short*)(ws + 19 * MB + 256 * KB);
  unsigned short* kb_ = (unsigned short*)(ws + 27 * MB + 256 * KB);
  unsigned short* vt  = (unsigned short*)(ws + 35 * MB + 256 * KB);  // vT from gemm1
  unsigned short* attn = (unsigned short*)(ws + 0);       // aliases xb (dead after gemm1)

  cvt_all<<<8452, 256, 0, stream>>>(x, wqw, wkw, wvw, wow, wqb, wkb, wvb, wobf,
                                    fc, fs, xb, wqkvb, wobb, biasq, biaso, fcT4, fsT4);
  gemm_qkv<<<dim3(16, 12), 512, 0, stream>>>(xb, wqkvb, biasq, qb_, kb_, vt, fcT4, fsT4, 1024);
  flash_kernel<<<1024, 512, 0, stream>>>(qb_, kb_, vt, attn);
  gemm_out<<<dim3(32, 16), 256, 0, stream>>>(attn, wobb, biaso, out, 1024, 1024);
}